// Round 22
// baseline (112.117 us; speedup 1.0000x reference)
//
#include <hip/hip_runtime.h>

typedef __attribute__((ext_vector_type(8)))  __bf16 bvec8;
typedef __attribute__((ext_vector_type(4)))  __bf16 bvec4;
typedef __attribute__((ext_vector_type(16))) float  fvec16;
typedef __attribute__((ext_vector_type(8)))  short  svec8;

__device__ __forceinline__ void gload16(const void* g, void* l) {
    __builtin_amdgcn_global_load_lds(
        (const __attribute__((address_space(1))) void*)g,
        (__attribute__((address_space(3))) void*)l,
        16, 0, 0);
}

// ---- pack W[l][j][k][i] fp32 -> Wp bf16, K64-tile staged layout ----
// unit u: lane=u&63, iu=(u>>6)&7, kk=(u>>9)&3, ib=(u>>11)&1, t64=u>>12 (0..17)
// offset = ((t64*2+ib)*32 + kk*8 + iu)*64 + lane  (16B units)
// i = ib*256 + iu*32 + (lane&31) ; K = t64*64 + kk*16 + (lane>>5)*8 + e
__global__ __launch_bounds__(256) void pack_w(const float* __restrict__ W,
                                              __bf16* __restrict__ Wp) {
    int u = blockIdx.x * 256 + threadIdx.x;
    if (u >= 73728) return;
    int lane = u & 63;
    int iu   = (u >> 6) & 7;
    int kk   = (u >> 9) & 3;
    int ib   = (u >> 11) & 1;
    int t64  = u >> 12;
    int i  = ib * 256 + iu * 32 + (lane & 31);
    int K0 = t64 * 64 + kk * 16 + ((lane >> 5) << 3);
    bvec8 o;
#pragma unroll
    for (int e = 0; e < 8; ++e) {
        int K  = K0 + e;
        int jk = K >> 7;
        int l  = K & 127;
        int j  = (jk * 11) >> 5;              // jk/3 for jk<9
        int k  = jk - 3 * j;
        o[e] = (__bf16)W[((l * 9 + j * 3 + k) << 9) + i];
    }
    *(bvec8*)&Wp[(size_t)u * 8] = o;
}

// ---- main: m201-template port. block = 4 batches x 256 i, 512 thr = 8 waves ----
// wave wid: wq = wid&3 (64-i slice), wm = wid>>2 (2-batch half).
// per wave: mt4 (batch 2wm+(mt>>1), s-tile mt&1) x nt2 -> acc[4][2] = 128 AGPR.
// ys (4 batches x 78 rows x 128 l, XOR-swizzled) resident; W via global_load_lds
// into 2x32KB dbuf; 18 K64 tiles x 4 phases; counted vmcnt(4); raw s_barrier.
__global__ __launch_bounds__(512, 2) void conv_mfma(
    const float* __restrict__ x, const __bf16* __restrict__ Wp,
    float* __restrict__ out)
{
    extern __shared__ __align__(16) char smem[];
    __bf16* ys   = (__bf16*)smem;               // 4*78*256 B = 79872
    char*  wbufB = smem + 79872;                // 2 x 32768
    __bf16* xs   = (__bf16*)wbufB;              // build-time overlay (25088 B)

    const int tid  = threadIdx.x;
    const int lane = tid & 63;
    const int l31  = lane & 31;
    const int ls5  = lane >> 5;
    const int wid  = tid >> 6;
    const int wq   = wid & 3;                   // i-quarter within 256
    const int wm   = wid >> 2;                  // batch-pair half
    const int bm   = blockIdx.x;                // batch-block (4 batches)
    const int ib   = blockIdx.y;                // i-half (256)
    const int b0   = bm * 4;

    const float* xb  = x + (size_t)b0 * 12544;
    const char*  WpB = (const char*)Wp;

    // ---- build ys for 4 batches (xs overlays wbuf; staged before K-loop) ----
    for (int bb = 0; bb < 4; ++bb) {
        for (int it = 0; it < 7; ++it) {
            int e4 = it * 512 + tid;
            if (e4 < 3136) {
                const float4 v = ((const float4*)(xb + bb * 12544))[e4];
                bvec4 pk = { (__bf16)v.x, (__bf16)v.y, (__bf16)v.z, (__bf16)v.w };
                *(bvec4*)&xs[e4 * 4] = pk;
            }
        }
        __syncthreads();
        for (int it = 0; it < 3; ++it) {
            int up = it * 512 + tid;
            if (up < 1248) {
                int row  = up >> 4;
                int useg = up & 15;
                int l0   = useg * 8;
                bvec8 ov;
                if (row == 77) {
                    ov = __builtin_bit_cast(bvec8, (svec8)0);
                } else if (row < 63) {
                    int t = row / 7, w = row - t * 7;
                    int tb = t + 5; if (tb >= 7) tb -= 7;
                    int cB = tb * 7 + w;
                    bool mA = (t >= 1) && (t <= 7);
                    int cA = mA ? (t - 1) * 7 + w : 0;
#pragma unroll
                    for (int d = 0; d < 8; ++d) {
                        float fa = mA ? (float)xs[(l0 + d) * 49 + cA] : 0.f;
                        float fb = (float)xs[(128 + l0 + d) * 49 + cB];
                        ov[d] = (__bf16)(fa + fb);
                    }
                } else if (row < 70) {
                    int w = row - 63;
#pragma unroll
                    for (int d = 0; d < 8; ++d) ov[d] = xs[(l0 + d) * 49 + w];
                } else {
                    int w = row - 70;
#pragma unroll
                    for (int d = 0; d < 8; ++d) ov[d] = xs[(l0 + d) * 49 + 7 + w];
                }
                *(bvec8*)&ys[((bb * 78 + row) << 7) + ((useg ^ (row & 15)) << 3)] = ov;
            }
        }
        __syncthreads();   // ys[bb] done; xs reusable (last: xs dead -> wbuf)
    }

    // ---- geometry per s-tile ----
    int nq[2], oo[2];
#pragma unroll
    for (int sn = 0; sn < 2; ++sn) {
        int s = sn * 32 + l31;
        int sc = (s < 49) ? s : 48;
        nq[sn] = sc / 7;
        oo[sn] = sc - nq[sn] * 7;
    }
    const int bb2[2] = { (2 * wm) * 9984, (2 * wm + 1) * 9984 };

    fvec16 acc[4][2];
#pragma unroll
    for (int mt = 0; mt < 4; ++mt)
#pragma unroll
        for (int nt = 0; nt < 2; ++nt)
#pragma unroll
            for (int r = 0; r < 16; ++r) acc[mt][nt][r] = 0.f;

#define STAGE(T, SLOT) {                                                      \
        const char* g_ = WpB + (((size_t)(T) * 2 + ib) << 15) + tid * 16;     \
        char* d_ = wbufB + (SLOT) * 32768 + tid * 16;                         \
        _Pragma("unroll")                                                     \
        for (int r_ = 0; r_ < 4; ++r_)                                        \
            gload16(g_ + r_ * 8192, d_ + r_ * 8192);                          \
    }

#define BARRIER() { asm volatile("" ::: "memory");                            \
        __builtin_amdgcn_s_barrier();                                         \
        asm volatile("" ::: "memory"); }

    // prologue: stage tiles 0,1 (after build barrier; xs dead)
    STAGE(0, 0)
    STAGE(1, 1)

    int rowE[2], rx[2];
    for (int jk = 0; jk < 9; ++jk) {
        {   // GEO(jk)
            int j_ = (jk * 11) >> 5; int k_ = jk - 3 * j_;
#pragma unroll
            for (int sn = 0; sn < 2; ++sn) {
                int tw = oo[sn] + k_ + 5; int w = tw >= 7 ? tw - 7 : tw;
                int row = (nq[sn] + j_) * 7 + w;
                if (nq[sn] == 1 && j_ == 0) row = 63 + w;
                if (nq[sn] == 0 && j_ == 2) row = 70 + w;
                if ((k_ == 0 && oo[sn] == 0) || (k_ == 2 && oo[sn] == 6)) row = 77;
                rowE[sn] = row << 7; rx[sn] = row & 15;
            }
        }
#pragma unroll
        for (int half = 0; half < 2; ++half) {
            const int t   = jk * 2 + half;
            const int cur = t & 1;
            // tile boundary: counted wait (last tile: full drain), then barrier
            if (t == 17) { asm volatile("s_waitcnt vmcnt(0)" ::: "memory"); }
            else        { asm volatile("s_waitcnt vmcnt(4)" ::: "memory"); }
            BARRIER()
            const char* ws = wbufB + cur * 32768;
#pragma unroll
            for (int p = 0; p < 4; ++p) {
                bvec8 wa[2], bf[4];
#pragma unroll
                for (int nt = 0; nt < 2; ++nt)
                    wa[nt] = *(const bvec8*)(ws + ((p * 8 + wq * 2 + nt) << 10)
                                             + lane * 16);
#pragma unroll
                for (int mt = 0; mt < 4; ++mt) {
                    const int sn = mt & 1;
                    const int u  = (half * 8 + p * 2 + ls5) ^ rx[sn];
                    bf[mt] = *(const bvec8*)&ys[bb2[mt >> 1] + rowE[sn] + (u << 3)];
                }
                __builtin_amdgcn_s_setprio(1);
#pragma unroll
                for (int mt = 0; mt < 4; ++mt)
#pragma unroll
                    for (int nt = 0; nt < 2; ++nt)
                        acc[mt][nt] = __builtin_amdgcn_mfma_f32_32x32x16_bf16(
                            wa[nt], bf[mt], acc[mt][nt], 0, 0, 0);
                __builtin_amdgcn_s_setprio(0);
                BARRIER()   // phase barrier; after p=3 also guards slot overwrite
            }
            if (t + 2 < 18) STAGE(t + 2, cur)
        }
    }

#undef STAGE
#undef BARRIER

    // ---- epilogue: direct stores. D row=(r&3)+8*(r>>2)+4*ls5 -> i ; col=l31 -> s ----
#pragma unroll
    for (int mt = 0; mt < 4; ++mt) {
        const int sn = mt & 1;
        if (sn == 1 && l31 >= 17) continue;   // s >= 49
        const int s = sn * 32 + l31;
        const size_t ob = (size_t)(b0 + 2 * wm + (mt >> 1)) * 25088;
#pragma unroll
        for (int nt = 0; nt < 2; ++nt) {
            const int i0 = ib * 256 + wq * 64 + nt * 32 + 4 * ls5;
#pragma unroll
            for (int r = 0; r < 16; ++r) {
                int i = i0 + (r & 3) + 8 * (r >> 2);
                out[ob + (size_t)i * 49 + s] = acc[mt][nt][r];
            }
        }
    }
}

extern "C" void kernel_launch(void* const* d_in, const int* in_sizes, int n_in,
                              void* d_out, int out_size, void* d_ws, size_t ws_size,
                              hipStream_t stream) {
    const float* x = (const float*)d_in[0];   // (1024,256,7,7)
    const float* W = (const float*)d_in[1];   // (128,3,3,512)
    float* out = (float*)d_out;               // (1024,512,7,7)
    __bf16* Wp = (__bf16*)d_ws;               // 73728*8 bf16 = 1.18 MB
    (void)in_sizes; (void)n_in; (void)out_size; (void)ws_size;

    hipFuncSetAttribute(reinterpret_cast<const void*>(conv_mfma),
                        hipFuncAttributeMaxDynamicSharedMemorySize, 145408);

    hipLaunchKernelGGL(pack_w, dim3(288), dim3(256), 0, stream, W, Wp);
    hipLaunchKernelGGL(conv_mfma, dim3(256, 2), dim3(512), 145408, stream, x, Wp, out);
}

// Round 23
// 106.868 us; speedup vs baseline: 1.0491x; 1.0491x over previous
//
#include <hip/hip_runtime.h>

typedef __attribute__((ext_vector_type(8)))  __bf16 bvec8;
typedef __attribute__((ext_vector_type(4)))  __bf16 bvec4;
typedef __attribute__((ext_vector_type(16))) float  fvec16;
typedef __attribute__((ext_vector_type(8)))  short  svec8;

__device__ __forceinline__ void gload16(const void* g, void* l) {
    __builtin_amdgcn_global_load_lds(
        (const __attribute__((address_space(1))) void*)g,
        (__attribute__((address_space(3))) void*)l,
        16, 0, 0);
}

// ---- pack W[l][j][k][i] fp32 -> Wp bf16 (R14 layout, proven) ----
// byte offset = t*32768 + it2*2048 + h*1024 + lane*16 ; i = it2*32+(lane&31),
// K = (2t+h)*16 + (lane>>5)*8 + e
__global__ __launch_bounds__(256) void pack_w(const float* __restrict__ W,
                                              __bf16* __restrict__ Wp) {
    int u = blockIdx.x * 256 + threadIdx.x;
    if (u >= 73728) return;
    int lane = u & 63;
    int h    = (u >> 6) & 1;
    int it   = (u >> 7) & 15;
    int t    = u >> 11;
    int i  = (it << 5) + (lane & 31);
    int K0 = ((2 * t + h) << 4) + ((lane >> 5) << 3);
    bvec8 o;
#pragma unroll
    for (int e = 0; e < 8; ++e) {
        int K  = K0 + e;
        int jk = K >> 7;
        int l  = K & 127;
        int j  = (jk * 11) >> 5;              // jk/3 for jk<9
        int k  = jk - 3 * j;
        o[e] = (__bf16)W[((l * 9 + j * 3 + k) << 9) + i];
    }
    *(bvec8*)&Wp[(size_t)u * 8] = o;
}

// ---- build_ys: materialize dedup'd activation panels to GLOBAL ----
// ysG[b] = 78 rows x 128 l bf16 (19968 B), XOR swizzle (useg^(row&15)) baked in.
// rows 0..62 (t=n+j): maskA*xA[t-1,w] + xB[(t+5)%7,w]; 63..69 xA[0,w];
// 70..76 xA[1,w]; 77 zeros.
__global__ __launch_bounds__(256) void build_ys(const float* __restrict__ x,
                                                __bf16* __restrict__ ysG) {
    __shared__ __bf16 xs[12544];
    const int tid = threadIdx.x;
    const int b   = blockIdx.x;
    const float* xb = x + (size_t)b * 12544;
    for (int it = 0; it < 13; ++it) {
        int e4 = it * 256 + tid;
        if (e4 < 3136) {
            const float4 v = ((const float4*)xb)[e4];
            bvec4 pk = { (__bf16)v.x, (__bf16)v.y, (__bf16)v.z, (__bf16)v.w };
            *(bvec4*)&xs[e4 * 4] = pk;
        }
    }
    __syncthreads();
    char* yb = (char*)ysG + (size_t)b * 19968;
    for (int it = 0; it < 5; ++it) {
        int up = it * 256 + tid;
        if (up < 1248) {
            int row  = up >> 4;
            int useg = up & 15;
            int l0   = useg * 8;
            bvec8 ov;
            if (row == 77) {
                ov = __builtin_bit_cast(bvec8, (svec8)0);
            } else if (row < 63) {
                int t = row / 7, w = row - t * 7;
                int tb = t + 5; if (tb >= 7) tb -= 7;
                int cB = tb * 7 + w;
                bool mA = (t >= 1) && (t <= 7);
                int cA = mA ? (t - 1) * 7 + w : 0;
#pragma unroll
                for (int d = 0; d < 8; ++d) {
                    float fa = mA ? (float)xs[(l0 + d) * 49 + cA] : 0.f;
                    float fb = (float)xs[(128 + l0 + d) * 49 + cB];
                    ov[d] = (__bf16)(fa + fb);
                }
            } else if (row < 70) {
                int w = row - 63;
#pragma unroll
                for (int d = 0; d < 8; ++d) ov[d] = xs[(l0 + d) * 49 + w];
            } else {
                int w = row - 70;
#pragma unroll
                for (int d = 0; d < 8; ++d) ov[d] = xs[(l0 + d) * 49 + 7 + w];
            }
            *(bvec8*)(yb + (row << 8) + ((useg ^ (row & 15)) << 4)) = ov;
        }
    }
}

// ---- main GEMM: global-M tiling, ZERO M-padding ----
// M = 50176 rows (g -> batch g/49, s g%49). Block: rows [bx*128,+128) x 256 i.
// 512 thr = 8 waves = wm2 (mt2: 2 m-tiles of 32) x wn4 (nt2: 64 i).
// acc[mt2][nt2] = 64 AGPR; W dist-2 reg-dbuf (aE/aO). Per K32 step:
// 4 ds_read : 8 MFMA : 4 W b128 (R20's proven shape). 2 blocks/CU (LDS 78 KB).
// ys slices (<=4 batches) staged from ysG via global_load_lds.
__global__ __launch_bounds__(512, 4) void conv_mfma(
    const __bf16* __restrict__ ysG, const __bf16* __restrict__ Wp,
    float* __restrict__ out)
{
    extern __shared__ __align__(16) char smem[];
    __bf16* ys = (__bf16*)smem;               // 4 slices x 19968 B = 79872 B

    const int tid  = threadIdx.x;
    const int lane = tid & 63;
    const int l31  = lane & 31;
    const int ls5  = lane >> 5;
    const int wid  = tid >> 6;
    const int wn   = wid & 3;                 // n-group: 64 i
    const int wm   = wid >> 2;                // m-group: 2 m-tiles
    const int ib   = blockIdx.y;              // i-half (256)
    const int g0   = blockIdx.x * 128;        // global row base
    const int bb0  = g0 / 49;                 // first batch in block

    const char* WpB = (const char*)Wp;
    const int wbase = (ib * 8 + wn * 2) * 2048 + lane * 16;

    // ---- W prologue: tiles 0,1 into dbuf regs (land during ys staging) ----
    bvec8 aE[2][2], aO[2][2];                 // [nt][h]
#pragma unroll
    for (int nt = 0; nt < 2; ++nt)
#pragma unroll
        for (int h = 0; h < 2; ++h) {
            aE[nt][h] = *(const bvec8*)(WpB + wbase + nt * 2048 + h * 1024);
            aO[nt][h] = *(const bvec8*)(WpB + 32768 + wbase + nt * 2048 + h * 1024);
        }

    // ---- stage 4 ys slices (clamped) via global_load_lds DMA ----
    {
        const char* ysGB = (const char*)ysG;
#pragma unroll
        for (int r = 0; r < 10; ++r) {
            int v = r * 512 + tid;
            if (v < 4992) {                   // 4 slices x 1248 16B-units
                int sl  = v / 1248;
                int off = v - sl * 1248;
                int bsl = bb0 + sl; if (bsl > 1023) bsl = 1023;
                gload16(ysGB + (size_t)bsl * 19968 + off * 16,
                        smem + v * 16);
            }
        }
    }

    // ---- per-lane row geometry (per mt): g -> batch, s, slice ----
    int ysb[2], nq[2], oo[2], bOut[2], sOut[2];
#pragma unroll
    for (int mt = 0; mt < 2; ++mt) {
        int g  = g0 + (wm * 2 + mt) * 32 + l31;
        int bb = g / 49;
        int s  = g - bb * 49;
        ysb[mt]  = (bb - bb0) * 9984;
        nq[mt]   = s / 7;
        oo[mt]   = s - nq[mt] * 7;
        bOut[mt] = bb;
        sOut[mt] = s;
    }

    fvec16 acc[2][2];                          // [mt][nt]
#pragma unroll
    for (int mt = 0; mt < 2; ++mt)
#pragma unroll
        for (int nt = 0; nt < 2; ++nt)
#pragma unroll
            for (int r = 0; r < 16; ++r) acc[mt][nt][r] = 0.f;

    __syncthreads();   // ys staged (vmcnt drained); no further barriers

#define GEO(JK) {                                                             \
        int j_ = ((JK) * 11) >> 5; int k_ = (JK) - 3 * j_;                    \
        _Pragma("unroll")                                                     \
        for (int mt_ = 0; mt_ < 2; ++mt_) {                                   \
            int tw_ = oo[mt_] + k_ + 5; int w_ = tw_ >= 7 ? tw_ - 7 : tw_;    \
            int row_ = (nq[mt_] + j_) * 7 + w_;                               \
            if (nq[mt_] == 1 && j_ == 0) row_ = 63 + w_;                      \
            if (nq[mt_] == 0 && j_ == 2) row_ = 70 + w_;                      \
            if ((k_ == 0 && oo[mt_] == 0) || (k_ == 2 && oo[mt_] == 6))       \
                row_ = 77;                                                    \
            rowE[mt_] = ysb[mt_] + (row_ << 7); rx[mt_] = row_ & 15; } }

    // per K32 step: for h(2){ for mt(2){ 1 bf read; 2 MFMA } }; prefetch tile
    // TNEXT into AW (the buffer just consumed) AFTER the MFMA cluster.
#define STEP(P, AW, TNEXT, DOPF) {                                            \
        _Pragma("unroll")                                                     \
        for (int h_ = 0; h_ < 2; ++h_)                                        \
        _Pragma("unroll")                                                     \
        for (int mt_ = 0; mt_ < 2; ++mt_) {                                   \
            int u_ = ((P) * 4 + h_ * 2 + ls5) ^ rx[mt_];                      \
            bvec8 bf_ = *(const bvec8*)&ys[rowE[mt_] + (u_ << 3)];            \
            __builtin_amdgcn_s_setprio(1);                                    \
            _Pragma("unroll")                                                 \
            for (int nt_ = 0; nt_ < 2; ++nt_)                                 \
                acc[mt_][nt_] = __builtin_amdgcn_mfma_f32_32x32x16_bf16(      \
                    AW[nt_][h_], bf_, acc[mt_][nt_], 0, 0, 0);                \
            __builtin_amdgcn_s_setprio(0);                                    \
        }                                                                     \
        if (DOPF) {                                                           \
            const char* gp_ = WpB + ((size_t)(TNEXT) << 15) + wbase;          \
            _Pragma("unroll")                                                 \
            for (int nt_ = 0; nt_ < 2; ++nt_)                                 \
            _Pragma("unroll")                                                 \
            for (int h_ = 0; h_ < 2; ++h_)                                    \
                AW[nt_][h_] = *(const bvec8*)(gp_ + nt_ * 2048 + h_ * 1024);  \
        } }

    // ---- K-loop: 9 jk x 4 steps, barrier-free, dist-2 W dbuf (R20 verbatim) ----
    int rowE[2], rx[2];
    for (int jk = 0; jk < 9; ++jk) {
        const int t0 = jk * 4;
        GEO(jk);
        STEP(0, aE, t0 + 2, true)
        STEP(1, aO, t0 + 3, true)
        STEP(2, aE, t0 + 4, (jk < 8))
        STEP(3, aO, t0 + 5, (jk < 8))
    }

#undef GEO
#undef STEP

    // ---- epilogue: D row=(r&3)+8*(r>>2)+4*ls5 -> i ; col=l31 -> row g ----
#pragma unroll
    for (int mt = 0; mt < 2; ++mt) {
        const size_t ob = (size_t)bOut[mt] * 25088 + sOut[mt];
#pragma unroll
        for (int nt = 0; nt < 2; ++nt) {
            const int i0 = ib * 256 + wn * 64 + nt * 32 + 4 * ls5;
#pragma unroll
            for (int r = 0; r < 16; ++r) {
                int i = i0 + (r & 3) + 8 * (r >> 2);
                out[ob + (size_t)i * 49] = acc[mt][nt][r];
            }
        }
    }
}

extern "C" void kernel_launch(void* const* d_in, const int* in_sizes, int n_in,
                              void* d_out, int out_size, void* d_ws, size_t ws_size,
                              hipStream_t stream) {
    const float* x = (const float*)d_in[0];   // (1024,256,7,7)
    const float* W = (const float*)d_in[1];   // (128,3,3,512)
    float* out = (float*)d_out;               // (1024,512,7,7)
    __bf16* Wp  = (__bf16*)d_ws;              // 1179648 B
    __bf16* ysG = (__bf16*)((char*)d_ws + 1179648);  // 1024*19968 B = 20.4 MB
    (void)in_sizes; (void)n_in; (void)out_size; (void)ws_size;

    hipFuncSetAttribute(reinterpret_cast<const void*>(conv_mfma),
                        hipFuncAttributeMaxDynamicSharedMemorySize, 79872);

    hipLaunchKernelGGL(pack_w, dim3(288), dim3(256), 0, stream, W, Wp);
    hipLaunchKernelGGL(build_ys, dim3(1024), dim3(256), 0, stream, x, ysG);
    hipLaunchKernelGGL(conv_mfma, dim3(392, 2), dim3(512), 79872, stream,
                       ysG, Wp, out);
}